// Round 6
// baseline (117.083 us; speedup 1.0000x reference)
//
#include <hip/hip_runtime.h>
#include <stdint.h>

#define NAC 147456   // 128*128*9
#define NGT 64
#define NB  8
#define APT 1        // r15: one anchor/thread -> 4608 blocks, 8 resident/CU
#define BLK 256
#define GX  (NAC / (BLK * APT))   // 576 -> grid 576x8 = 4608 blocks (18/CU stream)

// ---------------- Threefry-2x32 (JAX-compatible, 20 rounds) ----------------
__host__ __device__ static inline uint32_t tf_rotl(uint32_t x, uint32_t d) {
  return (x << d) | (x >> (32u - d));
}

__host__ __device__ static inline void threefry2x32(
    uint32_t k0, uint32_t k1, uint32_t x0, uint32_t x1,
    uint32_t* o0, uint32_t* o1)
{
  const uint32_t ks2 = k0 ^ k1 ^ 0x1BD11BDAu;
  x0 += k0; x1 += k1;
#define TFR(r) { x0 += x1; x1 = tf_rotl(x1, (r)); x1 ^= x0; }
  TFR(13u) TFR(15u) TFR(26u) TFR(6u)   x0 += k1;  x1 += ks2 + 1u;
  TFR(17u) TFR(29u) TFR(16u) TFR(24u)  x0 += ks2; x1 += k0 + 2u;
  TFR(13u) TFR(15u) TFR(26u) TFR(6u)   x0 += k0;  x1 += k1 + 3u;
  TFR(17u) TFR(29u) TFR(16u) TFR(24u)  x0 += k1;  x1 += ks2 + 4u;
  TFR(13u) TFR(15u) TFR(26u) TFR(6u)   x0 += ks2; x1 += k0 + 5u;
#undef TFR
  *o0 = x0; *o1 = x1;
}

__device__ static inline void bbox2delta_store(
    const float4& a, const float4& g, float* dst)
{
  const float wr  = a.w - a.y,          hr  = a.z - a.x;
  const float xcr = a.y + 0.5f * wr,    ycr = a.x + 0.5f * hr;
  const float wrc = fmaxf(wr, 1e-5f),   hrc = fmaxf(hr, 1e-5f);
  const float wl  = g.w - g.y,          hl  = g.z - g.x;
  const float xcl = g.y + 0.5f * wl,    ycl = g.x + 0.5f * hl;
  float4 r;
  r.x = fminf(fmaxf((xcl - xcr) / wrc, -10.0f), 10.0f);
  r.y = fminf(fmaxf((ycl - ycr) / hrc, -10.0f), 10.0f);
  r.z = fminf(fmaxf(__logf(wl / wrc),  -10.0f), 10.0f);
  r.w = fminf(fmaxf(__logf(hl / hrc),  -10.0f), 10.0f);
  *reinterpret_cast<float4*>(dst) = r;
}

// ---------------- Kernel 1: IoU argmax + proposals + flags + block count -----
// Round-15. k1 pinned at ~43us across THREE structurally different loops
// (dense r2 / SMEM r1 / deep-pipelined r4) -> not issue-structure-limited.
// OccupancyPercent ~30 taken at face value = ~2.4 waves/SIMD resident, which
// makes the kernel LATENCY-bound (chain depth ~7 per j-step, not enough TLP);
// the 80% VALUBusy is then gfx94x-formula inflation (both can't be true).
// Experiment: APT=1 -> 4608 blocks (18/CU streamed, 8 resident = 32 waves/CU,
// FULL occupancy; VGPR ~32, LDS 1.5KB block nothing). Cost: 3x LDS broadcast
// reads + 3x prologues (broadcast b128 is conflict-free; should stay hidden).
// DISCRIMINATOR: occupancy-limited -> k1 ~27-33us & Occupancy>=60;
//                issue-limited    -> k1 ~43us unchanged -> structural floor.
// Also: drop 2nd fmax(,0) — EXACT: update requires inter*Tb > num*Tj >= 0,
// impossible when either gap <= 0 (IEEE: -0>+0 and 0>0 are false); whenever
// stored, num == reference intersection bit-exactly (both gaps > 0).
// pos threshold BIT-IDENTICAL: epilogue recomputes den in reference rounding
// order, ONE IEEE div per anchor.
template <bool USE_FLAGS>
__global__ __launch_bounds__(BLK) void k1_classify(
    const float* __restrict__ anchors,
    const float* __restrict__ gt,
    const float* __restrict__ deltas,
    float* __restrict__ out,
    int* __restrict__ cnt_blk,          // USE_FLAGS: [NB*GX]; else counts[NB]
    unsigned char* __restrict__ flags)
{
  __shared__ __align__(16) float4 gbox[NGT];
  __shared__ __align__(16) float  garea[NGT];   // ga_j (exact, epilogue den)
  __shared__ __align__(16) float  gae[NGT];     // ga_j + EPS (T_j in compare)
  __shared__ int s_cnt;
  const int b   = blockIdx.y;
  const int tid = threadIdx.x;

  if (tid == 0) s_cnt = 0;
  if (tid < NGT) {
    float4 g = reinterpret_cast<const float4*>(gt)[b * NGT + tid];
    const float ga = fmaxf(g.z - g.x, 0.0f) * fmaxf(g.w - g.y, 0.0f);
    gbox[tid]  = g;
    garea[tid] = ga;
    gae[tid]   = ga + 1e-5f;
  }
  __syncthreads();

  const int i = blockIdx.x * BLK + tid;

  const float4 a = reinterpret_cast<const float4*>(anchors)[i];
  const float areaA = fmaxf(a.z - a.x, 0.0f) * fmaxf(a.w - a.y, 0.0f);
  float num  = 0.0f;   // incumbent inter
  float Tb   = 1.0f;   // incumbent S+e; any >0 gives "update iff inter>0" init
  int   bidx = 0;

#define IOU_ONE(gv, te, jv)                                              \
  {                                                                      \
    const float4 g_ = (gv);                                              \
    float yi = fmaxf(a.x, g_.x);                                         \
    float xi = fmaxf(a.y, g_.y);                                         \
    float ya = fminf(a.z, g_.z);                                         \
    float xa = fminf(a.w, g_.w);                                         \
    float inter = fmaxf(ya - yi, 0.0f) * (xa - xi);                      \
    float Tj = areaA + (te);                                             \
    bool upd = inter * Tb > num * Tj;                                    \
    num  = upd ? inter : num;                                            \
    Tb   = upd ? Tj    : Tb;                                             \
    bidx = upd ? (jv)  : bidx;                                           \
  }

  for (int jj = 0; jj < NGT; jj += 4) {
    const float4 te4 = *reinterpret_cast<const float4*>(&gae[jj]);
    const float4 g0 = gbox[jj + 0];
    const float4 g1 = gbox[jj + 1];
    const float4 g2 = gbox[jj + 2];
    const float4 g3 = gbox[jj + 3];
    IOU_ONE(g0, te4.x, jj + 0)
    IOU_ONE(g1, te4.y, jj + 1)
    IOU_ONE(g2, te4.z, jj + 2)
    IOU_ONE(g3, te4.w, jj + 3)
  }
#undef IOU_ONE

  // Exact reference rounding order for the pos test:
  // den = ((areaA + ga_best) - inter_best) + EPS ; iou = (10000*inter)/den
  const float gaB = garea[bidx];
  const float den = ((areaA + gaB) - num) + 1e-5f;
  const float best_iou = (10000.0f * num) / den;
  const bool pos = best_iou > 5000.0f;

  const float4 d = reinterpret_cast<const float4*>(deltas)[b * NAC + i];
  const float wb = a.w - a.y, hb = a.z - a.x;
  const float xc = a.y + 0.5f * wb + wb * d.x;
  const float yc = a.x + 0.5f * hb + hb * d.y;
  const float w_ = wb * __expf(d.z);
  const float h_ = hb * __expf(d.w);

  float* rowp = out + ((size_t)b * NAC + i) * 8;
  reinterpret_cast<float4*>(rowp)[0] =
      make_float4(yc - 0.5f * h_, xc - 0.5f * w_, yc + 0.5f * h_, xc + 0.5f * w_);
  if (USE_FLAGS) {
    reinterpret_cast<float4*>(rowp)[1] = make_float4(0.f, 0.f, 0.f, 0.f);
    flags[(size_t)b * NAC + i] = pos ? (unsigned char)(bidx + 1) : 0u;
  } else {
    reinterpret_cast<float4*>(rowp)[1] =
        make_float4(pos ? (float)(bidx + 1) : 0.0f, 0.f, 0.f, 0.f);
  }

  unsigned long long m = __ballot(pos);
  int npos = ((tid & 63) == 0) ? (int)__popcll(m) : 0;
  if (npos)
    atomicAdd(&s_cnt, npos);
  __syncthreads();

  if (tid == 0) {
    if (USE_FLAGS) cnt_blk[b * GX + blockIdx.x] = s_cnt;  // written once, no memset
    else if (s_cnt) atomicAdd(&cnt_blk[b], s_cnt);
  }
}

// ---------------- Kernel 2a (flags): sum block counts, sparse sampling -------
__global__ __launch_bounds__(256) void k2_flags(
    const float* __restrict__ anchors,
    const float* __restrict__ gt,
    float* __restrict__ out,
    const int* __restrict__ cnt_blk,
    const unsigned char* __restrict__ flags,
    uint32_t kp0, uint32_t kp1)
{
  __shared__ int s_tot;
  const int b   = blockIdx.y;
  const int tid = threadIdx.x;

  if (tid == 0) s_tot = 0;
  __syncthreads();
  int part = 0;
  for (int x = tid; x < GX; x += 256) part += cnt_blk[b * GX + x];
  if (part) atomicAdd(&s_tot, part);
  __syncthreads();
  const float th = 128.0f / ((float)s_tot + 1e-6f);

  const int chunk = blockIdx.x * 256 + tid;   // 16 rows per thread
  uint4 fv = reinterpret_cast<const uint4*>(flags + (size_t)b * NAC)[chunk];
  if ((fv.x | fv.y | fv.z | fv.w) == 0u) return;

  const uint32_t words[4] = { fv.x, fv.y, fv.z, fv.w };
  const int base_i = chunk * 16;

#pragma unroll
  for (int w = 0; w < 4; ++w) {
    uint32_t wd = words[w];
    while (wd) {
      const int byte = __ffs(wd) / 8;        // flag <= 64 keeps byte MSB clear
      const int fl   = (wd >> (byte * 8)) & 0xFF;
      wd &= ~(0xFFu << (byte * 8));
      const int i = base_i + w * 4 + byte;
      const int f = b * NAC + i;

      uint32_t o0, o1;
      threefry2x32(kp0, kp1, 0u, (uint32_t)f, &o0, &o1);
      const uint32_t bits = o0 ^ o1;
      union { uint32_t u; float flt; } cv;
      cv.u = (bits >> 9) | 0x3F800000u;
      if (cv.flt - 1.0f < th) {
        const float4 a = reinterpret_cast<const float4*>(anchors)[i];
        const float4 g = reinterpret_cast<const float4*>(gt)[b * NGT + (fl - 1)];
        bbox2delta_store(a, g, out + (size_t)f * 8 + 4);
      }
    }
  }
}

// ---------------- Kernel 2b (fallback, proven): flag in out[4] ---------------
__global__ __launch_bounds__(256) void k2_fallback(
    const float* __restrict__ anchors,
    const float* __restrict__ gt,
    float* __restrict__ out,
    const int* __restrict__ counts,
    uint32_t kp0, uint32_t kp1)
{
  const int b = blockIdx.y;
  const int i = blockIdx.x * 256 + threadIdx.x;
  const int f = b * NAC + i;
  float* rowp = out + (size_t)f * 8;

  const float flag = rowp[4];
  if (flag == 0.0f) return;

  const float th = 128.0f / ((float)counts[b] + 1e-6f);

  uint32_t o0, o1;
  threefry2x32(kp0, kp1, 0u, (uint32_t)f, &o0, &o1);
  const uint32_t bits = o0 ^ o1;
  union { uint32_t u; float flt; } cv;
  cv.u = (bits >> 9) | 0x3F800000u;

  if (cv.flt - 1.0f < th) {
    const float4 a = reinterpret_cast<const float4*>(anchors)[i];
    const float4 g = reinterpret_cast<const float4*>(gt)[b * NGT + ((int)flag - 1)];
    bbox2delta_store(a, g, rowp + 4);
  } else {
    reinterpret_cast<float4*>(rowp)[1] = make_float4(0.f, 0.f, 0.f, 0.f);
  }
}

extern "C" void kernel_launch(void* const* d_in, const int* in_sizes, int n_in,
                              void* d_out, int out_size, void* d_ws, size_t ws_size,
                              hipStream_t stream)
{
  const float* anchors = (const float*)d_in[0];
  const float* gt      = (const float*)d_in[1];
  const float* deltas  = (const float*)d_in[2];
  float* out  = (float*)d_out;
  int* cnt_blk = (int*)d_ws;                                // [NB*GX] ints = 18KB
  unsigned char* flags = (unsigned char*)d_ws + 32768;      // [NB*NAC] bytes

  const bool use_flags = ws_size >= (size_t)(32768 + NB * NAC);

  // kp = jax.random.split(jax.random.key(42))[0], threefry_partitionable:
  // kp = threefry2x32((0,42), 0, 0), full pair. (Verified rounds 2/3/5-9.)
  uint32_t kp0, kp1;
  threefry2x32(0u, 42u, 0u, 0u, &kp0, &kp1);

  dim3 g1(GX, NB);   // (576, 8) = 4608 blocks, 18/CU streamed, 8 resident
  if (use_flags) {
    k1_classify<true><<<g1, dim3(BLK), 0, stream>>>(anchors, gt, deltas, out,
                                                    cnt_blk, flags);
    dim3 g2(NAC / 16 / 256, NB);   // (36, 8)
    k2_flags<<<g2, dim3(256), 0, stream>>>(anchors, gt, out, cnt_blk, flags,
                                           kp0, kp1);
  } else {
    hipMemsetAsync(cnt_blk, 0, NB * sizeof(int), stream);
    k1_classify<false><<<g1, dim3(BLK), 0, stream>>>(anchors, gt, deltas, out,
                                                     cnt_blk, nullptr);
    dim3 g2(NAC / 256, NB);        // (576, 8)
    k2_fallback<<<g2, dim3(256), 0, stream>>>(anchors, gt, out, cnt_blk,
                                              kp0, kp1);
  }
}